// Round 2
// baseline (193.073 us; speedup 1.0000x reference)
//
#include <hip/hip_runtime.h>
#include <hip/hip_bf16.h>
#include <stdint.h>

#define TT 384   // num directions (num_thetas) for both spaces
#define NN 384   // num points
#define RR 384   // resolution
#define D1 128
#define D2 32

// ---------------- Threefry-2x32 (JAX), key = (0, 42) ----------------
__device__ inline void threefry2x32(uint32_t k0, uint32_t k1,
                                    uint32_t x0, uint32_t x1,
                                    uint32_t& o0, uint32_t& o1) {
    uint32_t ks2 = k0 ^ k1 ^ 0x1BD11BDAu;
    x0 += k0; x1 += k1;
    #define TF_ROUND(r) { x0 += x1; x1 = (x1 << (r)) | (x1 >> (32 - (r))); x1 ^= x0; }
    TF_ROUND(13) TF_ROUND(15) TF_ROUND(26) TF_ROUND(6)
    x0 += k1;  x1 += ks2 + 1u;
    TF_ROUND(17) TF_ROUND(29) TF_ROUND(16) TF_ROUND(24)
    x0 += ks2; x1 += k0 + 2u;
    TF_ROUND(13) TF_ROUND(15) TF_ROUND(26) TF_ROUND(6)
    x0 += k0;  x1 += k1 + 3u;
    TF_ROUND(17) TF_ROUND(29) TF_ROUND(16) TF_ROUND(24)
    x0 += k1;  x1 += ks2 + 4u;
    TF_ROUND(13) TF_ROUND(15) TF_ROUND(26) TF_ROUND(6)
    x0 += ks2; x1 += k0 + 5u;
    #undef TF_ROUND
    o0 = x0; o1 = x1;
}

// XLA f32 erf_inv (Giles polynomial)
__device__ inline float erfinv_f32(float x) {
    float w = -log1pf(-x * x);
    float p;
    if (w < 5.0f) {
        w = w - 2.5f;
        p =            2.81022636e-08f;
        p = fmaf(p, w, 3.43273939e-07f);
        p = fmaf(p, w, -3.5233877e-06f);
        p = fmaf(p, w, -4.39150654e-06f);
        p = fmaf(p, w, 0.00021858087f);
        p = fmaf(p, w, -0.00125372503f);
        p = fmaf(p, w, -0.00417768164f);
        p = fmaf(p, w, 0.246640727f);
        p = fmaf(p, w, 1.50140941f);
    } else {
        w = sqrtf(w) - 3.0f;
        p =            -0.000200214257f;
        p = fmaf(p, w, 0.000100950558f);
        p = fmaf(p, w, 0.00134934322f);
        p = fmaf(p, w, -0.00367342844f);
        p = fmaf(p, w, 0.00573950773f);
        p = fmaf(p, w, -0.0076224613f);
        p = fmaf(p, w, 0.00943887047f);
        p = fmaf(p, w, 1.00167406f);
        p = fmaf(p, w, 2.83297682f);
    }
    return p * x;
}

// bits -> jax.random.normal sample (f32)
__device__ inline float bits_to_normal(uint32_t bits) {
    uint32_t fb = (bits >> 9) | 0x3F800000u;
    float f = __uint_as_float(fb) - 1.0f;               // [0, 1)
    float lo = __uint_as_float(0xBF7FFFFFu);            // nextafter(-1, 0)
    float u = f * 2.0f + lo;   // (maxval-minval) rounds to 2.0f exactly (tie-to-even)
    u = fmaxf(lo, u);
    return 1.41421356237f * erfinv_f32(u);
}

// One block per column j (direction). blockDim.x = 128; threads i < d active.
// v shape [d, TT] row-major; flat rng index = i*TT + j.
// PARTITIONABLE threefry (modern JAX default): per-element block
// (x_hi = hi32(i) = 0, x_lo = i); bits = o0 ^ o1.
__global__ void gen_dirs(float* __restrict__ v, int d) {
    int j = blockIdx.x;
    int i = threadIdx.x;
    __shared__ float sh[128];
    float val = 0.0f;
    if (i < d) {
        uint32_t flat = (uint32_t)i * TT + (uint32_t)j;
        uint32_t o0, o1;
        threefry2x32(0u, 42u, 0u, flat, o0, o1);
        val = bits_to_normal(o0 ^ o1);
    }
    sh[i] = val * val;
    __syncthreads();
    for (int s = 64; s > 0; s >>= 1) {
        if (i < s) sh[i] += sh[i + s];
        __syncthreads();
    }
    float nrm = sqrtf(sh[0]);
    if (i < d) v[i * TT + j] = val / nrm;
}

// nh[n][t] = sum_k x[n][k] * v[k][t].  grid = (TT/128, NN), block = 128.
__global__ void proj_kernel(float* __restrict__ nh, const float* __restrict__ x,
                            const float* __restrict__ v, int d) {
    int t = blockIdx.x * 128 + threadIdx.x;
    int n = blockIdx.y;
    const float* xr = x + n * d;
    float acc = 0.0f;
    for (int k = 0; k < d; ++k)
        acc = fmaf(xr[k], v[k * TT + t], acc);
    nh[n * TT + t] = acc;
}

// One block per direction t; thread r = threshold index.
__global__ void ect_loss_kernel(const float* __restrict__ nh1,
                                const float* __restrict__ nh2,
                                float* __restrict__ out) {
    int t = blockIdx.x;
    int r = threadIdx.x;   // 0..383
    __shared__ float a[NN];
    __shared__ float b[NN];
    __shared__ float red[RR];
    for (int n = r; n < NN; n += blockDim.x) {
        a[n] = nh1[n * TT + t];
        b[n] = nh2[n * TT + t];
    }
    __syncthreads();
    float lin = -1.0f + 2.0f * (float)r / 383.0f;
    float e1 = 0.0f, e2 = 0.0f;
    for (int n = 0; n < NN; ++n) {
        e1 += 1.0f / (1.0f + __expf(500.0f * (a[n] - lin)));
        e2 += 1.0f / (1.0f + __expf(500.0f * (b[n] - lin)));
    }
    float diff = e1 - e2;
    red[r] = diff * diff;
    __syncthreads();
    if (r < 128) red[r] += red[r + 128] + red[r + 256];
    __syncthreads();
    for (int s = 64; s > 0; s >>= 1) {
        if (r < s) red[r] += red[r + s];
        __syncthreads();
    }
    if (r == 0) atomicAdd(out, red[0] * (1.0f / ((float)RR * (float)TT)));
}

extern "C" void kernel_launch(void* const* d_in, const int* in_sizes, int n_in,
                              void* d_out, int out_size, void* d_ws, size_t ws_size,
                              hipStream_t stream) {
    const float* space1 = (const float*)d_in[0];   // [384,128]
    const float* space2 = (const float*)d_in[1];   // [384,32]
    float* out = (float*)d_out;

    float* ws = (float*)d_ws;
    float* v1  = ws;                          // 128*384
    float* v2  = v1 + D1 * TT;                // 32*384
    float* nh1 = v2 + D2 * TT;                // 384*384
    float* nh2 = nh1 + NN * TT;               // 384*384

    hipMemsetAsync(d_out, 0, sizeof(float), stream);

    gen_dirs<<<TT, 128, 0, stream>>>(v1, D1);
    gen_dirs<<<TT, 128, 0, stream>>>(v2, D2);

    proj_kernel<<<dim3(TT / 128, NN), 128, 0, stream>>>(nh1, space1, v1, D1);
    proj_kernel<<<dim3(TT / 128, NN), 128, 0, stream>>>(nh2, space2, v2, D2);

    ect_loss_kernel<<<TT, RR, 0, stream>>>(nh1, nh2, out);
}

// Round 3
// 131.614 us; speedup vs baseline: 1.4670x; 1.4670x over previous
//
#include <hip/hip_runtime.h>
#include <hip/hip_bf16.h>
#include <stdint.h>

#define TT 384   // num directions (num_thetas) for both spaces
#define NN 384   // num points
#define RR 384   // resolution
#define D1 128
#define D2 32

// ---------------- Threefry-2x32 (JAX partitionable), key = (0, 42) ----------------
__device__ inline void threefry2x32(uint32_t k0, uint32_t k1,
                                    uint32_t x0, uint32_t x1,
                                    uint32_t& o0, uint32_t& o1) {
    uint32_t ks2 = k0 ^ k1 ^ 0x1BD11BDAu;
    x0 += k0; x1 += k1;
    #define TF_ROUND(r) { x0 += x1; x1 = (x1 << (r)) | (x1 >> (32 - (r))); x1 ^= x0; }
    TF_ROUND(13) TF_ROUND(15) TF_ROUND(26) TF_ROUND(6)
    x0 += k1;  x1 += ks2 + 1u;
    TF_ROUND(17) TF_ROUND(29) TF_ROUND(16) TF_ROUND(24)
    x0 += ks2; x1 += k0 + 2u;
    TF_ROUND(13) TF_ROUND(15) TF_ROUND(26) TF_ROUND(6)
    x0 += k0;  x1 += k1 + 3u;
    TF_ROUND(17) TF_ROUND(29) TF_ROUND(16) TF_ROUND(24)
    x0 += k1;  x1 += ks2 + 4u;
    TF_ROUND(13) TF_ROUND(15) TF_ROUND(26) TF_ROUND(6)
    x0 += ks2; x1 += k0 + 5u;
    #undef TF_ROUND
    o0 = x0; o1 = x1;
}

// XLA f32 erf_inv (Giles polynomial)
__device__ inline float erfinv_f32(float x) {
    float w = -log1pf(-x * x);
    float p;
    if (w < 5.0f) {
        w = w - 2.5f;
        p =            2.81022636e-08f;
        p = fmaf(p, w, 3.43273939e-07f);
        p = fmaf(p, w, -3.5233877e-06f);
        p = fmaf(p, w, -4.39150654e-06f);
        p = fmaf(p, w, 0.00021858087f);
        p = fmaf(p, w, -0.00125372503f);
        p = fmaf(p, w, -0.00417768164f);
        p = fmaf(p, w, 0.246640727f);
        p = fmaf(p, w, 1.50140941f);
    } else {
        w = sqrtf(w) - 3.0f;
        p =            -0.000200214257f;
        p = fmaf(p, w, 0.000100950558f);
        p = fmaf(p, w, 0.00134934322f);
        p = fmaf(p, w, -0.00367342844f);
        p = fmaf(p, w, 0.00573950773f);
        p = fmaf(p, w, -0.0076224613f);
        p = fmaf(p, w, 0.00943887047f);
        p = fmaf(p, w, 1.00167406f);
        p = fmaf(p, w, 2.83297682f);
    }
    return p * x;
}

__device__ inline float bits_to_normal(uint32_t bits) {
    uint32_t fb = (bits >> 9) | 0x3F800000u;
    float f = __uint_as_float(fb) - 1.0f;               // [0, 1)
    float lo = __uint_as_float(0xBF7FFFFFu);            // nextafter(-1, 0)
    float u = f * 2.0f + lo;
    u = fmaxf(lo, u);
    return 1.41421356237f * erfinv_f32(u);
}

// Fused: grid 768 blocks x 128 threads. Blocks [0,384) -> v1 (d=128),
// [384,768) -> v2 (d=32). Block 0 lane 0 also zero-inits the loss accumulator.
__global__ void gen_dirs_all(float* __restrict__ v1, float* __restrict__ v2,
                             float* __restrict__ out) {
    int bid = blockIdx.x;
    int i = threadIdx.x;
    if (bid == 0 && i == 0) out[0] = 0.0f;
    int j, d; float* v;
    if (bid < TT) { j = bid;      d = D1; v = v1; }
    else          { j = bid - TT; d = D2; v = v2; }
    __shared__ float sh[128];
    float val = 0.0f;
    if (i < d) {
        uint32_t flat = (uint32_t)i * TT + (uint32_t)j;
        uint32_t o0, o1;
        threefry2x32(0u, 42u, 0u, flat, o0, o1);
        val = bits_to_normal(o0 ^ o1);
    }
    sh[i] = val * val;
    __syncthreads();
    for (int s = 64; s > 0; s >>= 1) {
        if (i < s) sh[i] += sh[i + s];
        __syncthreads();
    }
    float nrm = sqrtf(sh[0]);
    if (i < d) v[i * TT + j] = val / nrm;
}

// Fused projection: grid (TT/128, NN, 2), block 128.
__global__ void proj_all(float* __restrict__ nh1, float* __restrict__ nh2,
                         const float* __restrict__ x1, const float* __restrict__ x2,
                         const float* __restrict__ v1, const float* __restrict__ v2) {
    int z = blockIdx.z;
    const float* x = z ? x2 : x1;
    const float* v = z ? v2 : v1;
    float* nh      = z ? nh2 : nh1;
    int d          = z ? D2 : D1;
    int t = blockIdx.x * 128 + threadIdx.x;
    int n = blockIdx.y;
    const float* xr = x + n * d;
    float acc = 0.0f;
    for (int k = 0; k < d; ++k)
        acc = fmaf(xr[k], v[k * TT + t], acc);
    nh[n * TT + t] = acc;
}

// grid (RR/128, TT), block 128: one (r,t) cell per thread.
__global__ void __launch_bounds__(128) ect_loss_kernel(
        const float* __restrict__ nh1, const float* __restrict__ nh2,
        float* __restrict__ out) {
    int t = blockIdx.y;
    int r = blockIdx.x * 128 + threadIdx.x;
    int tid = threadIdx.x;
    __shared__ float a[NN];
    __shared__ float b[NN];
    for (int n = tid; n < NN; n += 128) {
        a[n] = nh1[n * TT + t];
        b[n] = nh2[n * TT + t];
    }
    __syncthreads();
    float lin = -1.0f + 2.0f * (float)r / 383.0f;
    float e1 = 0.0f, e2 = 0.0f;
    #pragma unroll 4
    for (int n = 0; n < NN; ++n) {
        e1 += __builtin_amdgcn_rcpf(1.0f + __expf(500.0f * (a[n] - lin)));
        e2 += __builtin_amdgcn_rcpf(1.0f + __expf(500.0f * (b[n] - lin)));
    }
    float diff = e1 - e2;
    __shared__ float red[128];
    red[tid] = diff * diff;
    __syncthreads();
    for (int s = 64; s > 0; s >>= 1) {
        if (tid < s) red[tid] += red[tid + s];
        __syncthreads();
    }
    if (tid == 0) atomicAdd(out, red[0] * (1.0f / ((float)RR * (float)TT)));
}

extern "C" void kernel_launch(void* const* d_in, const int* in_sizes, int n_in,
                              void* d_out, int out_size, void* d_ws, size_t ws_size,
                              hipStream_t stream) {
    const float* space1 = (const float*)d_in[0];   // [384,128]
    const float* space2 = (const float*)d_in[1];   // [384,32]
    float* out = (float*)d_out;

    float* ws = (float*)d_ws;
    float* v1  = ws;                          // 128*384
    float* v2  = v1 + D1 * TT;                // 32*384
    float* nh1 = v2 + D2 * TT;                // 384*384
    float* nh2 = nh1 + NN * TT;               // 384*384

    gen_dirs_all<<<2 * TT, 128, 0, stream>>>(v1, v2, out);
    proj_all<<<dim3(TT / 128, NN, 2), 128, 0, stream>>>(nh1, nh2, space1, space2, v1, v2);
    ect_loss_kernel<<<dim3(RR / 128, TT), 128, 0, stream>>>(nh1, nh2, out);
}

// Round 4
// 124.797 us; speedup vs baseline: 1.5471x; 1.0546x over previous
//
#include <hip/hip_runtime.h>
#include <hip/hip_bf16.h>
#include <stdint.h>

#define TT 384   // num directions (num_thetas) for both spaces
#define NN 384   // num points
#define RR 384   // resolution
#define D1 128
#define D2 32

// Saturation threshold: sigmoid(500*y) == 1.0f exactly for y >= 17.33/500;
// < 3e-8 for y <= -17.6/500. 0.0352*500 = 17.6.
#define THETA 0.0352f

// ---------------- Threefry-2x32 (JAX partitionable), key = (0, 42) ----------------
__device__ inline void threefry2x32(uint32_t k0, uint32_t k1,
                                    uint32_t x0, uint32_t x1,
                                    uint32_t& o0, uint32_t& o1) {
    uint32_t ks2 = k0 ^ k1 ^ 0x1BD11BDAu;
    x0 += k0; x1 += k1;
    #define TF_ROUND(r) { x0 += x1; x1 = (x1 << (r)) | (x1 >> (32 - (r))); x1 ^= x0; }
    TF_ROUND(13) TF_ROUND(15) TF_ROUND(26) TF_ROUND(6)
    x0 += k1;  x1 += ks2 + 1u;
    TF_ROUND(17) TF_ROUND(29) TF_ROUND(16) TF_ROUND(24)
    x0 += ks2; x1 += k0 + 2u;
    TF_ROUND(13) TF_ROUND(15) TF_ROUND(26) TF_ROUND(6)
    x0 += k0;  x1 += k1 + 3u;
    TF_ROUND(17) TF_ROUND(29) TF_ROUND(16) TF_ROUND(24)
    x0 += k1;  x1 += ks2 + 4u;
    TF_ROUND(13) TF_ROUND(15) TF_ROUND(26) TF_ROUND(6)
    x0 += ks2; x1 += k0 + 5u;
    #undef TF_ROUND
    o0 = x0; o1 = x1;
}

// XLA f32 erf_inv (Giles polynomial)
__device__ inline float erfinv_f32(float x) {
    float w = -log1pf(-x * x);
    float p;
    if (w < 5.0f) {
        w = w - 2.5f;
        p =            2.81022636e-08f;
        p = fmaf(p, w, 3.43273939e-07f);
        p = fmaf(p, w, -3.5233877e-06f);
        p = fmaf(p, w, -4.39150654e-06f);
        p = fmaf(p, w, 0.00021858087f);
        p = fmaf(p, w, -0.00125372503f);
        p = fmaf(p, w, -0.00417768164f);
        p = fmaf(p, w, 0.246640727f);
        p = fmaf(p, w, 1.50140941f);
    } else {
        w = sqrtf(w) - 3.0f;
        p =            -0.000200214257f;
        p = fmaf(p, w, 0.000100950558f);
        p = fmaf(p, w, 0.00134934322f);
        p = fmaf(p, w, -0.00367342844f);
        p = fmaf(p, w, 0.00573950773f);
        p = fmaf(p, w, -0.0076224613f);
        p = fmaf(p, w, 0.00943887047f);
        p = fmaf(p, w, 1.00167406f);
        p = fmaf(p, w, 2.83297682f);
    }
    return p * x;
}

__device__ inline float bits_to_normal(uint32_t bits) {
    uint32_t fb = (bits >> 9) | 0x3F800000u;
    float f = __uint_as_float(fb) - 1.0f;               // [0, 1)
    float lo = __uint_as_float(0xBF7FFFFFu);            // nextafter(-1, 0)
    float u = f * 2.0f + lo;
    u = fmaxf(lo, u);
    return 1.41421356237f * erfinv_f32(u);
}

// grid 768 x 128. Blocks [0,384) -> v1 (d=128), [384,768) -> v2 (d=32).
// Block 0 lane 0 zero-inits the loss accumulator.
__global__ void gen_dirs_all(float* __restrict__ v1, float* __restrict__ v2,
                             float* __restrict__ out) {
    int bid = blockIdx.x;
    int i = threadIdx.x;
    if (bid == 0 && i == 0) out[0] = 0.0f;
    int j, d; float* v;
    if (bid < TT) { j = bid;      d = D1; v = v1; }
    else          { j = bid - TT; d = D2; v = v2; }
    __shared__ float sh[128];
    float val = 0.0f;
    if (i < d) {
        uint32_t flat = (uint32_t)i * TT + (uint32_t)j;
        uint32_t o0, o1;
        threefry2x32(0u, 42u, 0u, flat, o0, o1);
        val = bits_to_normal(o0 ^ o1);
    }
    sh[i] = val * val;
    __syncthreads();
    for (int s = 64; s > 0; s >>= 1) {
        if (i < s) sh[i] += sh[i + s];
        __syncthreads();
    }
    float nrm = sqrtf(sh[0]);
    if (i < d) v[i * TT + j] = val / nrm;
}

template<int D>
__device__ inline void proj_body(float* __restrict__ nh, const float* __restrict__ x,
                                 const float* __restrict__ v, int t, int n) {
    const float* xr = x + n * D;
    float acc = 0.0f;
    #pragma unroll 16
    for (int k = 0; k < D; ++k)
        acc = fmaf(xr[k], v[k * TT + t], acc);
    nh[n * TT + t] = acc;
}

// Fused projection: grid (TT/128, NN, 2), block 128.
__global__ void proj_all(float* __restrict__ nh1, float* __restrict__ nh2,
                         const float* __restrict__ x1, const float* __restrict__ x2,
                         const float* __restrict__ v1, const float* __restrict__ v2) {
    int t = blockIdx.x * 128 + threadIdx.x;
    int n = blockIdx.y;
    if (blockIdx.z == 0) proj_body<D1>(nh1, x1, v1, t, n);
    else                 proj_body<D2>(nh2, x2, v2, t, n);
}

// grid (RR/128, TT), block 128: one (r,t) cell per thread.
// Saturation-aware: sigmoid(500y) is exactly 1.0f for y>=THETA, <3e-8 for
// y<=-THETA. Only compute exp when some lane in the wave is in the band.
__global__ void __launch_bounds__(128) ect_loss_kernel(
        const float* __restrict__ nh1, const float* __restrict__ nh2,
        float* __restrict__ out) {
    int t = blockIdx.y;
    int r = blockIdx.x * 128 + threadIdx.x;
    int tid = threadIdx.x;
    __shared__ float a[NN];
    __shared__ float b[NN];
    for (int n = tid; n < NN; n += 128) {
        a[n] = nh1[n * TT + t];
        b[n] = nh2[n * TT + t];
    }
    __syncthreads();
    float lin = -1.0f + 2.0f * (float)r / 383.0f;
    float e1 = 0.0f, e2 = 0.0f;
    #pragma unroll 2
    for (int n = 0; n < NN; ++n) {
        float y1 = lin - a[n];
        float y2 = lin - b[n];
        float s1 = (y1 > 0.0f) ? 1.0f : 0.0f;
        float s2 = (y2 > 0.0f) ? 1.0f : 0.0f;
        bool in1 = fabsf(y1) < THETA;
        bool in2 = fabsf(y2) < THETA;
        if (__any(in1)) {
            float v = __builtin_amdgcn_rcpf(1.0f + __expf(-500.0f * y1));
            s1 = in1 ? v : s1;
        }
        if (__any(in2)) {
            float v = __builtin_amdgcn_rcpf(1.0f + __expf(-500.0f * y2));
            s2 = in2 ? v : s2;
        }
        e1 += s1;
        e2 += s2;
    }
    float diff = e1 - e2;
    float sq = diff * diff;
    // wave butterfly reduction (64 lanes)
    #pragma unroll
    for (int off = 32; off > 0; off >>= 1)
        sq += __shfl_xor(sq, off, 64);
    __shared__ float red[2];
    int wid = tid >> 6;
    if ((tid & 63) == 0) red[wid] = sq;
    __syncthreads();
    if (tid == 0)
        atomicAdd(out, (red[0] + red[1]) * (1.0f / ((float)RR * (float)TT)));
}

extern "C" void kernel_launch(void* const* d_in, const int* in_sizes, int n_in,
                              void* d_out, int out_size, void* d_ws, size_t ws_size,
                              hipStream_t stream) {
    const float* space1 = (const float*)d_in[0];   // [384,128]
    const float* space2 = (const float*)d_in[1];   // [384,32]
    float* out = (float*)d_out;

    float* ws = (float*)d_ws;
    float* v1  = ws;                          // 128*384
    float* v2  = v1 + D1 * TT;                // 32*384
    float* nh1 = v2 + D2 * TT;                // 384*384
    float* nh2 = nh1 + NN * TT;               // 384*384

    gen_dirs_all<<<2 * TT, 128, 0, stream>>>(v1, v2, out);
    proj_all<<<dim3(TT / 128, NN, 2), 128, 0, stream>>>(nh1, nh2, space1, space2, v1, v2);
    ect_loss_kernel<<<dim3(RR / 128, TT), 128, 0, stream>>>(nh1, nh2, out);
}

// Round 5
// 87.617 us; speedup vs baseline: 2.2036x; 1.4243x over previous
//
#include <hip/hip_runtime.h>
#include <hip/hip_bf16.h>
#include <stdint.h>

#define TT 384   // num directions
#define NN 384   // num points
#define RR 384   // resolution
#define D1 128
#define D2 32

// sigmoid(500y) == 1.0f (f32) for y >= 17.33/500; < 2.3e-8 for y <= -17.6/500.
#define THETA 0.0352f
#define HALF_SLOTS 191.5f          // 383/2: r(x) = (x+1)*191.5
#define BAND_ITERS 14              // ceil(2*THETA*191.5) = 14

// ---------------- Threefry-2x32 (JAX partitionable), key = (0, 42) ----------------
__device__ inline void threefry2x32(uint32_t k0, uint32_t k1,
                                    uint32_t x0, uint32_t x1,
                                    uint32_t& o0, uint32_t& o1) {
    uint32_t ks2 = k0 ^ k1 ^ 0x1BD11BDAu;
    x0 += k0; x1 += k1;
    #define TF_ROUND(r) { x0 += x1; x1 = (x1 << (r)) | (x1 >> (32 - (r))); x1 ^= x0; }
    TF_ROUND(13) TF_ROUND(15) TF_ROUND(26) TF_ROUND(6)
    x0 += k1;  x1 += ks2 + 1u;
    TF_ROUND(17) TF_ROUND(29) TF_ROUND(16) TF_ROUND(24)
    x0 += ks2; x1 += k0 + 2u;
    TF_ROUND(13) TF_ROUND(15) TF_ROUND(26) TF_ROUND(6)
    x0 += k0;  x1 += k1 + 3u;
    TF_ROUND(17) TF_ROUND(29) TF_ROUND(16) TF_ROUND(24)
    x0 += k1;  x1 += ks2 + 4u;
    TF_ROUND(13) TF_ROUND(15) TF_ROUND(26) TF_ROUND(6)
    x0 += ks2; x1 += k0 + 5u;
    #undef TF_ROUND
    o0 = x0; o1 = x1;
}

// XLA f32 erf_inv (Giles polynomial)
__device__ inline float erfinv_f32(float x) {
    float w = -log1pf(-x * x);
    float p;
    if (w < 5.0f) {
        w = w - 2.5f;
        p =            2.81022636e-08f;
        p = fmaf(p, w, 3.43273939e-07f);
        p = fmaf(p, w, -3.5233877e-06f);
        p = fmaf(p, w, -4.39150654e-06f);
        p = fmaf(p, w, 0.00021858087f);
        p = fmaf(p, w, -0.00125372503f);
        p = fmaf(p, w, -0.00417768164f);
        p = fmaf(p, w, 0.246640727f);
        p = fmaf(p, w, 1.50140941f);
    } else {
        w = sqrtf(w) - 3.0f;
        p =            -0.000200214257f;
        p = fmaf(p, w, 0.000100950558f);
        p = fmaf(p, w, 0.00134934322f);
        p = fmaf(p, w, -0.00367342844f);
        p = fmaf(p, w, 0.00573950773f);
        p = fmaf(p, w, -0.0076224613f);
        p = fmaf(p, w, 0.00943887047f);
        p = fmaf(p, w, 1.00167406f);
        p = fmaf(p, w, 2.83297682f);
    }
    return p * x;
}

__device__ inline float bits_to_normal(uint32_t bits) {
    uint32_t fb = (bits >> 9) | 0x3F800000u;
    float f = __uint_as_float(fb) - 1.0f;               // [0, 1)
    float lo = __uint_as_float(0xBF7FFFFFu);            // nextafter(-1, 0)
    float u = f * 2.0f + lo;
    u = fmaxf(lo, u);
    return 1.41421356237f * erfinv_f32(u);
}

// grid 768 x 128. Blocks [0,384) -> v1 (d=128), [384,768) -> v2 (d=32).
// Block 0 lane 0 zero-inits the loss accumulator.
__global__ void gen_dirs_all(float* __restrict__ v1, float* __restrict__ v2,
                             float* __restrict__ out) {
    int bid = blockIdx.x;
    int i = threadIdx.x;
    if (bid == 0 && i == 0) out[0] = 0.0f;
    int j, d; float* v;
    if (bid < TT) { j = bid;      d = D1; v = v1; }
    else          { j = bid - TT; d = D2; v = v2; }
    __shared__ float sh[128];
    float val = 0.0f;
    if (i < d) {
        uint32_t flat = (uint32_t)i * TT + (uint32_t)j;
        uint32_t o0, o1;
        threefry2x32(0u, 42u, 0u, flat, o0, o1);
        val = bits_to_normal(o0 ^ o1);
    }
    sh[i] = val * val;
    __syncthreads();
    for (int s = 64; s > 0; s >>= 1) {
        if (i < s) sh[i] += sh[i + s];
        __syncthreads();
    }
    float nrm = sqrtf(sh[0]);
    if (i < d) v[i * TT + j] = val / nrm;
}

template<int D>
__device__ inline void proj_body(float* __restrict__ nh, const float* __restrict__ x,
                                 const float* __restrict__ v, int t, int n) {
    const float* xr = x + n * D;
    float acc = 0.0f;
    #pragma unroll 16
    for (int k = 0; k < D; ++k)
        acc = fmaf(xr[k], v[k * TT + t], acc);
    nh[n * TT + t] = acc;
}

// Fused projection: grid (TT/128, NN, 2), block 128.
__global__ void proj_all(float* __restrict__ nh1, float* __restrict__ nh2,
                         const float* __restrict__ x1, const float* __restrict__ x2,
                         const float* __restrict__ v1, const float* __restrict__ v2) {
    int t = blockIdx.x * 128 + threadIdx.x;
    int n = blockIdx.y;
    if (blockIdx.z == 0) proj_body<D1>(nh1, x1, v1, t, n);
    else                 proj_body<D2>(nh2, x2, v2, t, n);
}

// Scatter one point's contribution (sign = +1 for space1, -1 for space2) into
// the difference histograms. step part: +sgn at r1 (then prefix-summed);
// band part: sgn * sigmoid at the ~14 r in the transition band.
__device__ inline void scatter_point(float p, float sgn,
                                     float* __restrict__ inc,
                                     float* __restrict__ band) {
    int r1  = (int)ceilf((p + (1.0f + THETA)) * HALF_SLOTS); // first r: lin_r >= p+theta
    int rlo = (int)ceilf((p + (1.0f - THETA)) * HALF_SLOTS); // first r: lin_r >= p-theta
    if (r1 <= 0)        atomicAdd(&inc[0], sgn);    // 1.0 everywhere in range
    else if (r1 <= 383) atomicAdd(&inc[r1], sgn);
    #pragma unroll
    for (int j = 0; j < BAND_ITERS; ++j) {
        int r = rlo + j;
        if (r >= 0 && r < r1 && r < RR) {
            float lin = -1.0f + 2.0f * (float)r / 383.0f;
            float sig = __builtin_amdgcn_rcpf(1.0f + __expf(500.0f * (p - lin)));
            atomicAdd(&band[r], sgn * sig);
        }
    }
}

// One block per direction t, 384 threads (= points = resolution slots).
__global__ void __launch_bounds__(384) ect_loss_kernel(
        const float* __restrict__ nh1, const float* __restrict__ nh2,
        float* __restrict__ out) {
    int t = blockIdx.x;
    int tid = threadIdx.x;
    __shared__ float inc[RR];    // step-function diff increments (prefix-summed)
    __shared__ float band[RR];   // transition-band diff values
    __shared__ float red[6];
    inc[tid] = 0.0f;
    band[tid] = 0.0f;
    __syncthreads();

    // gather this block's projection column (L2-resident, read exactly once)
    float p1 = nh1[tid * TT + t];
    float p2 = nh2[tid * TT + t];
    scatter_point(p1,  1.0f, inc, band);
    scatter_point(p2, -1.0f, inc, band);
    __syncthreads();

    // inclusive prefix sum over inc[0..383] (Hillis-Steele)
    for (int s = 1; s < RR; s <<= 1) {
        float v = inc[tid];
        if (tid >= s) v += inc[tid - s];
        __syncthreads();
        inc[tid] = v;
        __syncthreads();
    }

    float d = inc[tid] + band[tid];   // e1(r) - e2(r) at r = tid
    float sq = d * d;
    #pragma unroll
    for (int off = 32; off > 0; off >>= 1)
        sq += __shfl_xor(sq, off, 64);
    if ((tid & 63) == 0) red[tid >> 6] = sq;
    __syncthreads();
    if (tid == 0) {
        float s = red[0] + red[1] + red[2] + red[3] + red[4] + red[5];
        atomicAdd(out, s * (1.0f / ((float)RR * (float)TT)));
    }
}

extern "C" void kernel_launch(void* const* d_in, const int* in_sizes, int n_in,
                              void* d_out, int out_size, void* d_ws, size_t ws_size,
                              hipStream_t stream) {
    const float* space1 = (const float*)d_in[0];   // [384,128]
    const float* space2 = (const float*)d_in[1];   // [384,32]
    float* out = (float*)d_out;

    float* ws = (float*)d_ws;
    float* v1  = ws;                          // 128*384
    float* v2  = v1 + D1 * TT;                // 32*384
    float* nh1 = v2 + D2 * TT;                // 384*384
    float* nh2 = nh1 + NN * TT;               // 384*384

    gen_dirs_all<<<2 * TT, 128, 0, stream>>>(v1, v2, out);
    proj_all<<<dim3(TT / 128, NN, 2), 128, 0, stream>>>(nh1, nh2, space1, space2, v1, v2);
    ect_loss_kernel<<<TT, 384, 0, stream>>>(nh1, nh2, out);
}

// Round 6
// 86.702 us; speedup vs baseline: 2.2268x; 1.0106x over previous
//
#include <hip/hip_runtime.h>
#include <hip/hip_bf16.h>
#include <stdint.h>

#define TT 384   // num directions
#define NN 384   // num points
#define RR 384   // resolution
#define D1 128
#define D2 32

// sigmoid(500y) == 1.0f (f32) for y >= 17.33/500; < 2.3e-8 for y <= -17.6/500.
#define THETA 0.0352f
#define HALF_SLOTS 191.5f          // 383/2: r(x) = (x+1)*191.5
#define BAND_ITERS 14              // ceil(2*THETA*191.5) = 14

// ---------------- Threefry-2x32 (JAX partitionable), key = (0, 42) ----------------
__device__ inline void threefry2x32(uint32_t k0, uint32_t k1,
                                    uint32_t x0, uint32_t x1,
                                    uint32_t& o0, uint32_t& o1) {
    uint32_t ks2 = k0 ^ k1 ^ 0x1BD11BDAu;
    x0 += k0; x1 += k1;
    #define TF_ROUND(r) { x0 += x1; x1 = (x1 << (r)) | (x1 >> (32 - (r))); x1 ^= x0; }
    TF_ROUND(13) TF_ROUND(15) TF_ROUND(26) TF_ROUND(6)
    x0 += k1;  x1 += ks2 + 1u;
    TF_ROUND(17) TF_ROUND(29) TF_ROUND(16) TF_ROUND(24)
    x0 += ks2; x1 += k0 + 2u;
    TF_ROUND(13) TF_ROUND(15) TF_ROUND(26) TF_ROUND(6)
    x0 += k0;  x1 += k1 + 3u;
    TF_ROUND(17) TF_ROUND(29) TF_ROUND(16) TF_ROUND(24)
    x0 += k1;  x1 += ks2 + 4u;
    TF_ROUND(13) TF_ROUND(15) TF_ROUND(26) TF_ROUND(6)
    x0 += ks2; x1 += k0 + 5u;
    #undef TF_ROUND
    o0 = x0; o1 = x1;
}

// XLA f32 erf_inv (Giles polynomial)
__device__ inline float erfinv_f32(float x) {
    float w = -log1pf(-x * x);
    float p;
    if (w < 5.0f) {
        w = w - 2.5f;
        p =            2.81022636e-08f;
        p = fmaf(p, w, 3.43273939e-07f);
        p = fmaf(p, w, -3.5233877e-06f);
        p = fmaf(p, w, -4.39150654e-06f);
        p = fmaf(p, w, 0.00021858087f);
        p = fmaf(p, w, -0.00125372503f);
        p = fmaf(p, w, -0.00417768164f);
        p = fmaf(p, w, 0.246640727f);
        p = fmaf(p, w, 1.50140941f);
    } else {
        w = sqrtf(w) - 3.0f;
        p =            -0.000200214257f;
        p = fmaf(p, w, 0.000100950558f);
        p = fmaf(p, w, 0.00134934322f);
        p = fmaf(p, w, -0.00367342844f);
        p = fmaf(p, w, 0.00573950773f);
        p = fmaf(p, w, -0.0076224613f);
        p = fmaf(p, w, 0.00943887047f);
        p = fmaf(p, w, 1.00167406f);
        p = fmaf(p, w, 2.83297682f);
    }
    return p * x;
}

__device__ inline float bits_to_normal(uint32_t bits) {
    uint32_t fb = (bits >> 9) | 0x3F800000u;
    float f = __uint_as_float(fb) - 1.0f;               // [0, 1)
    float lo = __uint_as_float(0xBF7FFFFFu);            // nextafter(-1, 0)
    float u = f * 2.0f + lo;
    u = fmaxf(lo, u);
    return 1.41421356237f * erfinv_f32(u);
}

// Transpose both spaces (x[n][k] -> xT[k][n]) and zero the loss accumulator.
// Grid 240 x 256 covers 49152 + 12288 elements.
__global__ void prep_kernel(float* __restrict__ xT1, float* __restrict__ xT2,
                            const float* __restrict__ x1, const float* __restrict__ x2,
                            float* __restrict__ out) {
    int idx = blockIdx.x * 256 + threadIdx.x;
    if (idx == 0) out[0] = 0.0f;
    if (idx < D1 * TT) {
        int k = idx / NN, n = idx % NN;
        xT1[idx] = x1[n * D1 + k];
    } else {
        int idx2 = idx - D1 * TT;
        if (idx2 < D2 * TT) {
            int k = idx2 / NN, n = idx2 % NN;
            xT2[idx2] = x2[n * D2 + k];
        }
    }
}

// Scatter one point's contribution (sign = +1 for space1, -1 for space2) into
// the difference histograms. step part: +sgn at r1 (prefix-summed later);
// band part: sgn * sigmoid at the ~14 r in the transition band.
__device__ inline void scatter_point(float p, float sgn,
                                     float* __restrict__ inc,
                                     float* __restrict__ band) {
    int r1  = (int)ceilf((p + (1.0f + THETA)) * HALF_SLOTS); // first r: lin_r >= p+theta
    int rlo = (int)ceilf((p + (1.0f - THETA)) * HALF_SLOTS); // first r: lin_r >= p-theta
    if (r1 <= 0)        atomicAdd(&inc[0], sgn);
    else if (r1 <= 383) atomicAdd(&inc[r1], sgn);
    #pragma unroll
    for (int j = 0; j < BAND_ITERS; ++j) {
        int r = rlo + j;
        if (r >= 0 && r < r1 && r < RR) {
            float lin = -1.0f + 2.0f * (float)r / 383.0f;
            float sig = __builtin_amdgcn_rcpf(1.0f + __expf(500.0f * (p - lin)));
            atomicAdd(&band[r], sgn * sig);
        }
    }
}

// Fully fused: one block per direction t. 384 threads.
// Phase 1: RNG + normalize both direction columns (160 normals).
// Phase 2: GEMV — thread n computes p1 = <x1[n,:], v1col>, p2 likewise.
// Phase 3: histogram scatter + wave-shuffle prefix scan + loss reduce.
__global__ void __launch_bounds__(384) ect_fused(
        const float* __restrict__ xT1, const float* __restrict__ xT2,
        float* __restrict__ out) {
    int t = blockIdx.x;
    int tid = threadIdx.x;
    int lane = tid & 63;
    int w = tid >> 6;                 // wave id, 0..5
    __shared__ float v1s[D1];
    __shared__ float v2s[D2];
    __shared__ float inc[RR];
    __shared__ float band[RR];
    __shared__ float red[8];

    // ---- Phase 1: directions ----
    float g = 0.0f;
    if (tid < D1 + D2) {
        int i = (tid < D1) ? tid : tid - D1;
        uint32_t flat = (uint32_t)i * TT + (uint32_t)t;
        uint32_t o0, o1;
        threefry2x32(0u, 42u, 0u, flat, o0, o1);
        g = bits_to_normal(o0 ^ o1);
    }
    float sq = g * g;                 // waves 0,1 -> v1; wave 2 lanes<32 -> v2
    #pragma unroll
    for (int off = 32; off > 0; off >>= 1) sq += __shfl_xor(sq, off, 64);
    if (lane == 0) red[w] = sq;
    __syncthreads();
    float nrm1 = sqrtf(red[0] + red[1]);
    float nrm2 = sqrtf(red[2]);
    if (tid < D1)           v1s[tid] = g / nrm1;
    else if (tid < D1 + D2) v2s[tid - D1] = g / nrm2;
    inc[tid] = 0.0f;
    band[tid] = 0.0f;
    __syncthreads();

    // ---- Phase 2: GEMV (coalesced across n; v from LDS broadcast) ----
    int n = tid;
    float p1 = 0.0f, p2 = 0.0f;
    #pragma unroll 8
    for (int k = 0; k < D1; ++k) p1 = fmaf(xT1[k * NN + n], v1s[k], p1);
    #pragma unroll 8
    for (int k = 0; k < D2; ++k) p2 = fmaf(xT2[k * NN + n], v2s[k], p2);

    // ---- Phase 3: histogram ----
    scatter_point(p1,  1.0f, inc, band);
    scatter_point(p2, -1.0f, inc, band);
    __syncthreads();

    // inclusive prefix scan over inc[0..383]: wave shuffle scan + wave offsets
    float v = inc[tid];
    #pragma unroll
    for (int s = 1; s < 64; s <<= 1) {
        float u = __shfl_up(v, s, 64);
        if (lane >= s) v += u;
    }
    if (lane == 63) red[w] = v;       // wave totals
    __syncthreads();
    float off_acc = 0.0f;
    for (int j = 0; j < w; ++j) off_acc += red[j];
    v += off_acc;

    float d = v + band[tid];          // e1(r) - e2(r) at r = tid
    float s2 = d * d;
    #pragma unroll
    for (int off = 32; off > 0; off >>= 1) s2 += __shfl_xor(s2, off, 64);
    __syncthreads();                  // protect red[] reuse
    if (lane == 0) red[w] = s2;
    __syncthreads();
    if (tid == 0) {
        float s = red[0] + red[1] + red[2] + red[3] + red[4] + red[5];
        atomicAdd(out, s * (1.0f / ((float)RR * (float)TT)));
    }
}

extern "C" void kernel_launch(void* const* d_in, const int* in_sizes, int n_in,
                              void* d_out, int out_size, void* d_ws, size_t ws_size,
                              hipStream_t stream) {
    const float* space1 = (const float*)d_in[0];   // [384,128]
    const float* space2 = (const float*)d_in[1];   // [384,32]
    float* out = (float*)d_out;

    float* ws = (float*)d_ws;
    float* xT1 = ws;                  // 128*384
    float* xT2 = xT1 + D1 * TT;       // 32*384

    prep_kernel<<<240, 256, 0, stream>>>(xT1, xT2, space1, space2, out);
    ect_fused<<<TT, 384, 0, stream>>>(xT1, xT2, out);
}